// Round 11
// baseline (291.842 us; speedup 1.0000x reference)
//
#include <hip/hip_runtime.h>

// ---------------------------------------------------------------------------
// Fused attention block on MI355X.  B=2 T=2048 DIM=2048 NH=32 NKV=8 HD=64
// W=1024.  f16 MFMA 16x16x32 everywhere; fixed-max exp2 softmax in attention.
// GEMMs: minimal-barrier free-run schedule (round-10, measured good), re-tiled
// BM=256 -> BM=128 so LDS fits 2 blocks/CU (16 waves/CU vs 8): QKV 128x192
// (80KB LDS), wo 128x128 (64KB).  Guide m103/m112: at this structure class
// 128-tiles (912 TF, multi-block/CU) beat 256-tiles (792 TF).
// Attention: EXACT round-7/10 kernel (control, ~77us measured).
// ---------------------------------------------------------------------------

typedef _Float16 f16;
typedef __attribute__((ext_vector_type(8))) _Float16 f16x8;
typedef __attribute__((ext_vector_type(4))) _Float16 f16x4;
typedef __attribute__((ext_vector_type(2))) _Float16 f16x2;
typedef __attribute__((ext_vector_type(4))) float f32x4;

#define T_ 2048
#define NH 32
#define NKV 8
#define HD 64
#define WINDOW 1024
#define EPS_ 1e-6f
#define LOG2E 1.44269504088896340736f
#define LDQKV 3072

__device__ inline void async16(void* lds, const void* g) {
  __builtin_amdgcn_global_load_lds(
      (const __attribute__((address_space(1))) unsigned int*)g,
      (__attribute__((address_space(3))) unsigned int*)lds, 16, 0, 0);
}

// --------------------------- fp32 -> f16 (fused) ---------------------------
struct CvtArgs {
  const float* src[5];
  f16* dst[5];
  int n4[5];
};
__global__ __launch_bounds__(256) void cvt_multi(CvtArgs a) {
  const int seg = blockIdx.y;
  const float* in = a.src[seg];
  f16* out = a.dst[seg];
  const int n4 = a.n4[seg];
  for (int i = blockIdx.x * blockDim.x + threadIdx.x; i < n4;
       i += gridDim.x * blockDim.x) {
    float4 v = ((const float4*)in)[i];
    f16x4 o;
    o[0] = (f16)v.x; o[1] = (f16)v.y; o[2] = (f16)v.z; o[3] = (f16)v.w;
    ((f16x4*)out)[i] = o;
  }
}

#define DSRD(p, off) (*(const f16x8*)((p) + (off)))

// ------------------ BMxBN minimal-barrier NT GEMM (unified) ----------------
// C[M,N] = A[M,K] * B[N,K]^T.  f16 in, f16/f32 out with ldc.
// 512 threads = 8 waves (2M x 4N), per-wave (BM/2) x (BN/4).  BK=64.
// Free-run per K-tile: stage next tile (other buffer) -> ds_reads+MFMAs with
// compiler-scheduled lgkmcnt -> vmcnt(0)+barrier once per tile.
// LDS: 2*(BM+BN)*128 bytes.  BM=128,BN=192 -> 80KB (2 blocks/CU);
// BM=128,BN=128 -> 64KB (2 blocks/CU).
template <int BM, int BN>
__global__ __launch_bounds__(512, 4) void gemm_nt(const f16* __restrict__ A,
                                                  const f16* __restrict__ B,
                                                  void* __restrict__ C,
                                                  int M, int N, int K, int ldc,
                                                  int out_f32) {
  constexpr int WM = BM / 2;      // per-wave M rows (64)
  constexpr int IM = WM / 16;     // i-count (4)
  constexpr int WN = BN / 4;      // per-wave N cols (48 or 32)
  constexpr int JC = WN / 16;     // j-count (3 or 2)
  constexpr int RA = BM / 64;     // A staging rounds (2)
  constexpr int RB = BN / 64;     // B staging rounds (3 or 2)
  constexpr int ABUF = BM * 128;  // bytes per A buffer
  constexpr int BBUF = BN * 128;  // bytes per B buffer
  extern __shared__ char smem[];
  f16* sA = (f16*)smem;
  f16* sB = (f16*)(smem + 2 * ABUF);

  // XCD-bijective block swizzle (grids here are multiples of 8)
  const int gx = gridDim.x;
  const int nwg = gx * gridDim.y;
  int bid = blockIdx.y * gx + blockIdx.x;
  if (!(nwg & 7)) bid = (bid & 7) * (nwg >> 3) + (bid >> 3);
  const int m0 = (bid / gx) * BM;
  const int n0 = (bid % gx) * BN;

  const int tid = threadIdx.x;
  const int lane = tid & 63;
  const int wave = tid >> 6;
  const int quad = lane >> 4, l16 = lane & 15;
  const int wm = wave >> 2, wn = wave & 3;   // 2 x 4 wave grid

  // staging: round r covers rows [r*64, r*64+64), 8KB per round.
  // LDS dest linear; global source column pre-swizzled (granule ^ row&7).
  const int srow = tid >> 3;
  const int sgr = (((tid & 7) ^ (srow & 7))) * 8;
  const f16* gA = A + (size_t)(m0 + srow) * K + sgr;
  const f16* gB = B + (size_t)(n0 + srow) * K + sgr;
  const size_t r64 = (size_t)64 * K;

  const char* cA = (const char*)sA;
  const char* cB = (const char*)sB;
  const int xm = (l16 & 7) << 4;
  const int xk0 = (quad * 16) ^ xm;
  const int xk1 = (64 + quad * 16) ^ xm;
  const int abase = (wm * WM + l16) * 128;
  const int bbase = (wn * WN + l16) * 128;

  f32x4 acc[IM][JC] = {};
  const int nt = K >> 6;

  // prologue: stage tile 0, drain, barrier
#pragma unroll
  for (int a = 0; a < RA; ++a)
    async16(sA + a * 4096 + tid * 8, gA + (size_t)a * r64);
#pragma unroll
  for (int rb = 0; rb < RB; ++rb)
    async16(sB + rb * 4096 + tid * 8, gB + (size_t)rb * r64);
  asm volatile("s_waitcnt vmcnt(0)" ::: "memory");
  __builtin_amdgcn_s_barrier();

  for (int t = 0; t < nt; ++t) {
    const int bufoA = (t & 1) * ABUF;
    const int bufoB = (t & 1) * BBUF;
    const bool st = (t + 1 < nt);

    // issue next-tile staging into the other buffer (its last readers
    // completed before the barrier that ended iteration t-1)
    if (st) {
      f16* sAn = sA + ((t & 1) ^ 1) * (ABUF / 2);
      f16* sBn = sB + ((t & 1) ^ 1) * (BBUF / 2);
      const size_t gk = (size_t)(t + 1) * 64;
#pragma unroll
      for (int a = 0; a < RA; ++a)
        async16(sAn + a * 4096 + tid * 8, gA + a * r64 + gk);
#pragma unroll
      for (int rb = 0; rb < RB; ++rb)
        async16(sBn + rb * 4096 + tid * 8, gB + rb * r64 + gk);
    }

    // free-run: frags + MFMAs, compiler interleaves with counted lgkmcnt
    f16x8 bf[JC][2];
#pragma unroll
    for (int j = 0; j < JC; ++j) {
      bf[j][0] = DSRD(cB, bufoB + bbase + j * 2048 + xk0);
      bf[j][1] = DSRD(cB, bufoB + bbase + j * 2048 + xk1);
    }
    f16x8 a0[IM], a1[IM];
#pragma unroll
    for (int i = 0; i < IM; ++i) {
      a0[i] = DSRD(cA, bufoA + abase + i * 2048 + xk0);
      a1[i] = DSRD(cA, bufoA + abase + i * 2048 + xk1);
    }
#pragma unroll
    for (int i = 0; i < IM; ++i)
#pragma unroll
      for (int j = 0; j < JC; ++j) {
        acc[i][j] = __builtin_amdgcn_mfma_f32_16x16x32_f16(
            a0[i], bf[j][0], acc[i][j], 0, 0, 0);
        acc[i][j] = __builtin_amdgcn_mfma_f32_16x16x32_f16(
            a1[i], bf[j][1], acc[i][j], 0, 0, 0);
      }

    // single per-tile sync: staged tile landed (drain covered by MFMA body)
    if (st) {
      asm volatile("s_waitcnt vmcnt(0)" ::: "memory");
      __builtin_amdgcn_s_barrier();
    }
  }

#pragma unroll
  for (int i = 0; i < IM; ++i) {
    const int row0 = m0 + wm * WM + i * 16 + quad * 4;
#pragma unroll
    for (int j = 0; j < JC; ++j) {
      const int col = n0 + wn * WN + j * 16 + l16;
#pragma unroll
      for (int r = 0; r < 4; ++r) {
        const float v = acc[i][j][r];
        if (out_f32) ((float*)C)[(size_t)(row0 + r) * ldc + col] = v;
        else         ((f16*)C)[(size_t)(row0 + r) * ldc + col] = (f16)v;
      }
    }
  }
}

// ------------------------- RMSNorm (q and k fused) -------------------------
__global__ __launch_bounds__(256) void rmsnorm2(f16* __restrict__ xqkv,
                                                const float* __restrict__ qw,
                                                const float* __restrict__ kw) {
  __shared__ float red[4];
  const int which = blockIdx.y;                   // 0 = q(2048), 1 = k(512)
  const int tid = threadIdx.x;

  auto block_sum = [&](float ss) -> float {
#pragma unroll
    for (int off = 32; off > 0; off >>= 1) ss += __shfl_down(ss, off);
    if ((tid & 63) == 0) red[tid >> 6] = ss;
    __syncthreads();
    return red[0] + red[1] + red[2] + red[3];
  };

  if (which == 0) {
    f16* p = xqkv + (size_t)blockIdx.x * LDQKV;
    f16x8 v = ((const f16x8*)p)[tid];
    float f[8];
    float ss = 0.f;
#pragma unroll
    for (int j = 0; j < 8; ++j) { f[j] = (float)v[j]; ss += f[j] * f[j]; }
    const float scale = rsqrtf(block_sum(ss) / 2048.0f + EPS_);
    const float4 w0 = ((const float4*)qw)[tid * 2];
    const float4 w1 = ((const float4*)qw)[tid * 2 + 1];
    f16x8 o;
    o[0] = (f16)(f[0] * scale * w0.x); o[1] = (f16)(f[1] * scale * w0.y);
    o[2] = (f16)(f[2] * scale * w0.z); o[3] = (f16)(f[3] * scale * w0.w);
    o[4] = (f16)(f[4] * scale * w1.x); o[5] = (f16)(f[5] * scale * w1.y);
    o[6] = (f16)(f[6] * scale * w1.z); o[7] = (f16)(f[7] * scale * w1.w);
    ((f16x8*)p)[tid] = o;
  } else {
    f16* p = xqkv + (size_t)blockIdx.x * LDQKV + 2048;
    f16x2 v = ((const f16x2*)p)[tid];
    const float f0 = (float)v[0], f1 = (float)v[1];
    const float scale = rsqrtf(block_sum(f0 * f0 + f1 * f1) / 512.0f + EPS_);
    const float2 w = ((const float2*)kw)[tid];
    f16x2 o;
    o[0] = (f16)(f0 * scale * w.x);
    o[1] = (f16)(f1 * scale * w.y);
    ((f16x2*)p)[tid] = o;
  }
}

// ------------------- K/V -> fragment-major global layout -------------------
__global__ __launch_bounds__(256) void kvfrag(const f16* __restrict__ xqkv,
                                              f16* __restrict__ Kf,
                                              f16* __restrict__ Vf) {
  __shared__ f16 Lk[64][72];
  __shared__ f16 Lv[64][72];
  const int kt = blockIdx.x;
  const int b = blockIdx.y >> 3, kh = blockIdx.y & 7;
  const int t0 = kt * 64;
  const int tid = threadIdx.x;
  const int r = tid >> 3, c = (tid & 7) * 8;
#pragma unroll
  for (int rp = 0; rp < 2; ++rp) {
    const int rr = r + rp * 32;
    const f16* src = xqkv + (size_t)(b * T_ + t0 + rr) * LDQKV + kh * 64 + c;
    *(f16x8*)(&Lk[rr][c]) = *(const f16x8*)(src + 2048);
    *(f16x8*)(&Lv[rr][c]) = *(const f16x8*)(src + 2560);
  }
  __syncthreads();
  const size_t obase = ((size_t)(b * 8 + kh) * 32 + kt) * 4096;
#pragma unroll
  for (int cc0 = 0; cc0 < 2; ++cc0) {
    const int cc = tid + cc0 * 256;
    const int nb = cc >> 7, kc = (cc >> 6) & 1, ln = cc & 63;
    const int qd = ln >> 4, s16 = ln & 15;
    *(f16x8*)(Kf + obase + cc * 8) = *(const f16x8*)(&Lk[nb * 16 + s16][kc * 32 + qd * 8]);
    f16x8 o;
#pragma unroll
    for (int j = 0; j < 8; ++j) o[j] = Lv[kc * 32 + qd * 8 + j][nb * 16 + s16];
    *(f16x8*)(Vf + obase + cc * 8) = o;
  }
}

// ---------------------------- Flash attention ------------------------------
// EXACT round-7/10 kernel (~77us measured, control).  Grid: (qt2=16, h=32,
// b=2), 4 waves, barrier-free kt loop.  128 q rows per block: each wave owns
// TWO 16-row q-groups (qa/qb) sharing the same K/V fragment loads.
__global__ __launch_bounds__(256, 4) void attn(const f16* __restrict__ Q,
                                               const f16* __restrict__ Kf,
                                               const f16* __restrict__ Vf,
                                               f16* __restrict__ O) {
  constexpr int LDW = 72;
  __shared__ f16 Qs[128 * LDW];   // overlaid by per-wave P after q latch
  __shared__ float Lx[4][2][16];

  const int qt2 = 15 - blockIdx.x;   // heavy tiles dispatch first
  const int h = blockIdx.y, b = blockIdx.z;
  const int kh = h >> 2;
  const int q0 = qt2 * 128;
  const int tid = threadIdx.x;
  const int lane = tid & 63, wave = tid >> 6;
  const int quad = lane >> 4, l16 = lane & 15;
  const float scale2 = 0.125f * LOG2E;
  const float slope2 = exp2f(-0.25f * (float)h) * LOG2E;
  const float M2 = 10.0f;

  const int sr = tid >> 3, sc = (tid & 7) * 8;

  // stage Q tile (128 q x 64 d)
#pragma unroll
  for (int rp = 0; rp < 4; ++rp) {
    const int rr = sr + rp * 32;
    *(f16x8*)(Qs + rr * LDW + sc) =
        *(const f16x8*)(Q + (size_t)(b * T_ + q0 + rr) * LDQKV + h * HD + sc);
  }
  __syncthreads();   // the only block-wide barrier
  f16x8 qa[2], qb[2];
#pragma unroll
  for (int kc = 0; kc < 2; ++kc) {
    qa[kc] = *(const f16x8*)(Qs + (wave * 32 + l16) * LDW + kc * 32 + quad * 8);
    qb[kc] = *(const f16x8*)(Qs + (wave * 32 + 16 + l16) * LDW + kc * 32 + quad * 8);
  }
  f16* PsA = Qs + (wave * 32) * LDW;
  f16* PsB = Qs + (wave * 32 + 16) * LDW;

  f32x4 o0[4] = {}, o1[4] = {};
  float lsA = 0.f, lsB = 0.f;

  const int kt_lo = (q0 >= WINDOW) ? ((q0 - WINDOW) >> 6) : 0;
  const int kt_hi = (q0 + 127) >> 6;
  const int gA0 = q0 + wave * 32;
  const int gB0 = gA0 + 16;
  const int qA = gA0 + l16;
  const int qB = qA + 16;
  const f16* kfb = Kf + (size_t)(b * 8 + kh) * 131072 + lane * 8;
  const f16* vfb = Vf + (size_t)(b * 8 + kh) * 131072 + lane * 8;

  float sr4[4];
#pragma unroll
  for (int r = 0; r < 4; ++r) sr4[r] = slope2 * (float)r;
  float baseA = slope2 * (float)(kt_lo * 64 + quad * 4 - qA) - M2;
  float baseB = slope2 * (float)(kt_lo * 64 + quad * 4 - qB) - M2;
  const float bstep = slope2 * 64.0f;
  const float b16 = slope2 * 16.0f;

  for (int kt = kt_lo; kt <= kt_hi; ++kt) {
    const int k0 = kt * 64;
    const f16* kp = kfb + kt * 4096;
    const f16* vp = vfb + kt * 4096;
    const bool maskA = (k0 + 63 > gA0) || (k0 + WINDOW < gA0 + 15);
    const bool maskB = (k0 + 63 > gB0) || (k0 + WINDOW < gB0 + 15);

    float bnbA = baseA, bnbB = baseB;
#pragma unroll
    for (int nb = 0; nb < 4; ++nb) {
      const f16x8 k0f = *(const f16x8*)(kp + (nb * 2) * 512);
      const f16x8 k1f = *(const f16x8*)(kp + (nb * 2 + 1) * 512);
      f32x4 a = {0.f, 0.f, 0.f, 0.f};
      a = __builtin_amdgcn_mfma_f32_16x16x32_f16(k0f, qa[0], a, 0, 0, 0);
      a = __builtin_amdgcn_mfma_f32_16x16x32_f16(k1f, qa[1], a, 0, 0, 0);
      f32x4 c = {0.f, 0.f, 0.f, 0.f};
      c = __builtin_amdgcn_mfma_f32_16x16x32_f16(k0f, qb[0], c, 0, 0, 0);
      c = __builtin_amdgcn_mfma_f32_16x16x32_f16(k1f, qb[1], c, 0, 0, 0);

      f16x4 pkA, pkB;
#pragma unroll
      for (int r = 0; r < 4; ++r) {
        const int key = k0 + nb * 16 + quad * 4 + r;
        float vA = fmaf(a[r], scale2, bnbA + sr4[r]);
        if (maskA) {
          const int dist = key - qA;
          if (dist > 0 || dist < -WINDOW) vA = -1e30f;
        }
        const float pA = __builtin_amdgcn_exp2f(vA);
        lsA += pA;
        pkA[r] = (f16)pA;
        float vB = fmaf(c[r], scale2, bnbB + sr4[r]);
        if (maskB) {
          const int dist = key - qB;
          if (dist > 0 || dist < -WINDOW) vB = -1e30f;
        }
        const float pB = __builtin_amdgcn_exp2f(vB);
        lsB += pB;
        pkB[r] = (f16)pB;
      }
      *(f16x4*)(PsA + l16 * LDW + nb * 16 + quad * 4) = pkA;
      *(f16x4*)(PsB + l16 * LDW + nb * 16 + quad * 4) = pkB;
      bnbA += b16; bnbB += b16;
    }
    baseA += bstep; baseB += bstep;

    const f16x8 paA0 = *(const f16x8*)(PsA + l16 * LDW + quad * 8);
    const f16x8 paA1 = *(const f16x8*)(PsA + l16 * LDW + 32 + quad * 8);
    const f16x8 paB0 = *(const f16x8*)(PsB + l16 * LDW + quad * 8);
    const f16x8 paB1 = *(const f16x8*)(PsB + l16 * LDW + 32 + quad * 8);
#pragma unroll
    for (int nb = 0; nb < 4; ++nb) {
      const f16x8 v0 = *(const f16x8*)(vp + (nb * 2) * 512);
      const f16x8 v1 = *(const f16x8*)(vp + (nb * 2 + 1) * 512);
      o0[nb] = __builtin_amdgcn_mfma_f32_16x16x32_f16(paA0, v0, o0[nb], 0, 0, 0);
      o0[nb] = __builtin_amdgcn_mfma_f32_16x16x32_f16(paA1, v1, o0[nb], 0, 0, 0);
      o1[nb] = __builtin_amdgcn_mfma_f32_16x16x32_f16(paB0, v0, o1[nb], 0, 0, 0);
      o1[nb] = __builtin_amdgcn_mfma_f32_16x16x32_f16(paB1, v1, o1[nb], 0, 0, 0);
    }
  }

  lsA += __shfl_xor(lsA, 16);
  lsA += __shfl_xor(lsA, 32);
  lsB += __shfl_xor(lsB, 16);
  lsB += __shfl_xor(lsB, 32);
  if (quad == 0) { Lx[wave][0][l16] = lsA; Lx[wave][1][l16] = lsB; }
  float rlA[4], rlB[4];
#pragma unroll
  for (int r = 0; r < 4; ++r) {
    rlA[r] = 1.0f / Lx[wave][0][quad * 4 + r];
    rlB[r] = 1.0f / Lx[wave][1][quad * 4 + r];
  }

#pragma unroll
  for (int r = 0; r < 4; ++r) {
    const int qrA = q0 + wave * 32 + quad * 4 + r;
#pragma unroll
    for (int nb = 0; nb < 4; ++nb) {
      O[(size_t)(b * T_ + qrA) * (NH * HD) + h * HD + nb * 16 + l16] =
          (f16)(o0[nb][r] * rlA[r]);
      O[(size_t)(b * T_ + qrA + 16) * (NH * HD) + h * HD + nb * 16 + l16] =
          (f16)(o1[nb][r] * rlB[r]);
    }
  }
}

// ------------------------------- launcher ----------------------------------
extern "C" void kernel_launch(void* const* d_in, const int* in_sizes, int n_in,
                              void* d_out, int out_size, void* d_ws, size_t ws_size,
                              hipStream_t stream) {
  const float* x  = (const float*)d_in[0];
  const float* wq = (const float*)d_in[1];
  const float* wk = (const float*)d_in[2];
  const float* wv = (const float*)d_in[3];
  const float* wo = (const float*)d_in[4];
  const float* qw = (const float*)d_in[5];
  const float* kw = (const float*)d_in[6];
  float* out = (float*)d_out;

  char* ws = (char*)d_ws;
  size_t off = 0;
  auto carve = [&](size_t bytes) -> char* {
    char* p = ws + off;
    off += (bytes + 255) & ~(size_t)255;
    return p;
  };
  f16* xh    = (f16*)carve((size_t)4096 * 2048 * 2);  // x f16; later attn out
  f16* wqkvh = (f16*)carve((size_t)3072 * 2048 * 2);
  f16* woh   = (f16*)carve((size_t)2048 * 2048 * 2);
  f16* xqkv  = (f16*)carve((size_t)4096 * 3072 * 2);
  // After the QKV GEMM the wq rows of wqkvh are dead: reuse for K/V frags.
  f16* Kf = wqkvh;                          // 16 x 128K f16 = 4MB
  f16* Vf = wqkvh + (size_t)16 * 131072;    // 4MB
  f16* ao = xh;

  static bool attr_done = false;
  if (!attr_done) {
    (void)hipFuncSetAttribute((const void*)gemm_nt<128, 192>,
                              hipFuncAttributeMaxDynamicSharedMemorySize,
                              81920);
    (void)hipFuncSetAttribute((const void*)gemm_nt<128, 128>,
                              hipFuncAttributeMaxDynamicSharedMemorySize,
                              65536);
    attr_done = true;
  }

  CvtArgs ca;
  ca.src[0] = x;  ca.dst[0] = xh;                            ca.n4[0] = (4096 * 2048) / 4;
  ca.src[1] = wq; ca.dst[1] = wqkvh;                         ca.n4[1] = (2048 * 2048) / 4;
  ca.src[2] = wk; ca.dst[2] = wqkvh + (size_t)2048 * 2048;   ca.n4[2] = (512 * 2048) / 4;
  ca.src[3] = wv; ca.dst[3] = wqkvh + (size_t)2560 * 2048;   ca.n4[3] = (512 * 2048) / 4;
  ca.src[4] = wo; ca.dst[4] = woh;                           ca.n4[4] = (2048 * 2048) / 4;
  cvt_multi<<<dim3(1024, 5), 256, 0, stream>>>(ca);

  gemm_nt<128, 192><<<dim3(16, 32), 512, 81920, stream>>>(
      xh, wqkvh, xqkv, 4096, 3072, 2048, LDQKV, 0);
  rmsnorm2<<<dim3(4096, 2), 256, 0, stream>>>(xqkv, qw, kw);
  kvfrag<<<dim3(32, 16), 256, 0, stream>>>(xqkv, Kf, Vf);
  attn<<<dim3(16, 32, 2), 256, 0, stream>>>(xqkv, Kf, Vf, ao);
  gemm_nt<128, 128><<<dim3(16, 32), 512, 65536, stream>>>(
      ao, woh, out, 4096, 2048, 2048, 2048, 1);
}

// Round 12
// 280.334 us; speedup vs baseline: 1.0411x; 1.0411x over previous
//
#include <hip/hip_runtime.h>

// ---------------------------------------------------------------------------
// Fused attention block on MI355X.  B=2 T=2048 DIM=2048 NH=32 NKV=8 HD=64
// W=1024.  f16 MFMA 16x16x32 everywhere; fixed-max exp2 softmax in attention.
// EXACT round-10 configuration (281.7us, session best), reverted after the
// round-11 BM=128 re-tile regressed to 291.8 (halved per-wave MFMA work +
// doubled B-panel traffic outweighed 2-blocks/CU occupancy).
// GEMMs: minimal-barrier free-run schedule -- ONE barrier per K-tile; waves
// free-run ds_reads+MFMAs (compiler-scheduled lgkmcnt); staging targets the
// other buffer; vmcnt(0) drain covered by the ~1800cy MFMA body.
// Attention: round-7 kernel, 128 q rows/block, 2 q-groups per wave sharing
// K/V fragment loads (fragment-major global layout, L2-resident).
// ---------------------------------------------------------------------------

typedef _Float16 f16;
typedef __attribute__((ext_vector_type(8))) _Float16 f16x8;
typedef __attribute__((ext_vector_type(4))) _Float16 f16x4;
typedef __attribute__((ext_vector_type(2))) _Float16 f16x2;
typedef __attribute__((ext_vector_type(4))) float f32x4;

#define T_ 2048
#define NH 32
#define NKV 8
#define HD 64
#define WINDOW 1024
#define EPS_ 1e-6f
#define LOG2E 1.44269504088896340736f
#define LDQKV 3072

__device__ inline void async16(void* lds, const void* g) {
  __builtin_amdgcn_global_load_lds(
      (const __attribute__((address_space(1))) unsigned int*)g,
      (__attribute__((address_space(3))) unsigned int*)lds, 16, 0, 0);
}

// --------------------------- fp32 -> f16 (fused) ---------------------------
struct CvtArgs {
  const float* src[5];
  f16* dst[5];
  int n4[5];
};
__global__ __launch_bounds__(256) void cvt_multi(CvtArgs a) {
  const int seg = blockIdx.y;
  const float* in = a.src[seg];
  f16* out = a.dst[seg];
  const int n4 = a.n4[seg];
  for (int i = blockIdx.x * blockDim.x + threadIdx.x; i < n4;
       i += gridDim.x * blockDim.x) {
    float4 v = ((const float4*)in)[i];
    f16x4 o;
    o[0] = (f16)v.x; o[1] = (f16)v.y; o[2] = (f16)v.z; o[3] = (f16)v.w;
    ((f16x4*)out)[i] = o;
  }
}

#define DSRD(p, off) (*(const f16x8*)((p) + (off)))

// ------------------- 256x192 minimal-barrier NT GEMM (QKV) -----------------
// grid 16x16 = 256 blocks = 1/CU.  8 waves (2M x 4N), per-wave 128x48.
// One barrier per K-tile; free-run 22 ds_reads + 48 MFMAs between barriers.
__global__ __launch_bounds__(512, 1) void gemm_nt192(const f16* __restrict__ A,
                                                     const f16* __restrict__ B,
                                                     f16* __restrict__ C) {
  constexpr int K = 2048, ldc = 3072;
  extern __shared__ char smem[];
  f16* sA = (f16*)smem;              // 2 x 256x64 = 64KB
  f16* sB = (f16*)(smem + 65536);    // 2 x 192x64 = 48KB

  const int gx = gridDim.x;          // 16
  const int nwg = gx * gridDim.y;    // 256
  int bid = blockIdx.y * gx + blockIdx.x;
  bid = (bid & 7) * (nwg >> 3) + (bid >> 3);
  const int m0 = (bid / gx) * 256;
  const int n0 = (bid % gx) * 192;

  const int tid = threadIdx.x;
  const int lane = tid & 63;
  const int wave = tid >> 6;
  const int quad = lane >> 4, l16 = lane & 15;
  const int wm = wave >> 2, wn = wave & 3;   // 2 x 4 wave grid

  const int srow = tid >> 3;
  const int sgr = (((tid & 7) ^ (srow & 7))) * 8;
  const f16* gA = A + (size_t)(m0 + srow) * K + sgr;
  const f16* gB = B + (size_t)(n0 + srow) * K + sgr;
  const size_t r64 = (size_t)64 * K;

  const char* cA = (const char*)sA;
  const char* cB = (const char*)sB;
  const int xm = (l16 & 7) << 4;
  const int xk0 = (quad * 16) ^ xm;
  const int xk1 = (64 + quad * 16) ^ xm;
  const int abase = (wm * 128 + l16) * 128;
  const int bbase = (wn * 48 + l16) * 128;

  f32x4 acc[8][3] = {};
  const int nt = K >> 6;   // 32

  // prologue: stage tile 0, drain, barrier
#pragma unroll
  for (int a = 0; a < 4; ++a)
    async16(sA + a * 4096 + tid * 8, gA + (size_t)a * r64);
#pragma unroll
  for (int rb = 0; rb < 3; ++rb)
    async16(sB + rb * 4096 + tid * 8, gB + (size_t)rb * r64);
  asm volatile("s_waitcnt vmcnt(0)" ::: "memory");
  __builtin_amdgcn_s_barrier();

  for (int t = 0; t < nt; ++t) {
    const int bufoA = (t & 1) << 15;           // 32KB
    const int bufoB = (t & 1) * 24576;         // 24KB
    const bool st = (t + 1 < nt);

    // issue next-tile staging into the other buffer (its last readers
    // completed before the barrier that ended iteration t-1)
    if (st) {
      f16* sAn = sA + (((t & 1) ^ 1) << 14);
      f16* sBn = sB + ((t & 1) ^ 1) * 12288;
      const size_t gk = (size_t)(t + 1) * 64;
#pragma unroll
      for (int a = 0; a < 4; ++a)
        async16(sAn + a * 4096 + tid * 8, gA + a * r64 + gk);
#pragma unroll
      for (int rb = 0; rb < 3; ++rb)
        async16(sBn + rb * 4096 + tid * 8, gB + rb * r64 + gk);
    }

    // free-run: B frags once, then per-mh A frags + MFMAs.  No barriers --
    // the compiler interleaves ds_reads and MFMAs with counted lgkmcnt.
    f16x8 bf[3][2];
#pragma unroll
    for (int j = 0; j < 3; ++j) {
      bf[j][0] = DSRD(cB, bufoB + bbase + j * 2048 + xk0);
      bf[j][1] = DSRD(cB, bufoB + bbase + j * 2048 + xk1);
    }
#pragma unroll
    for (int mh = 0; mh < 2; ++mh) {
      f16x8 a0[4], a1[4];
#pragma unroll
      for (int i = 0; i < 4; ++i) {
        a0[i] = DSRD(cA, bufoA + abase + mh * 8192 + i * 2048 + xk0);
        a1[i] = DSRD(cA, bufoA + abase + mh * 8192 + i * 2048 + xk1);
      }
#pragma unroll
      for (int i = 0; i < 4; ++i)
#pragma unroll
        for (int j = 0; j < 3; ++j) {
          acc[mh * 4 + i][j] = __builtin_amdgcn_mfma_f32_16x16x32_f16(
              a0[i], bf[j][0], acc[mh * 4 + i][j], 0, 0, 0);
          acc[mh * 4 + i][j] = __builtin_amdgcn_mfma_f32_16x16x32_f16(
              a1[i], bf[j][1], acc[mh * 4 + i][j], 0, 0, 0);
        }
    }

    // single per-tile sync: staged tile landed (drain covered by the ~1800cy
    // MFMA body above), then all waves cross together.
    if (st) {
      asm volatile("s_waitcnt vmcnt(0)" ::: "memory");
      __builtin_amdgcn_s_barrier();
    }
  }

#pragma unroll
  for (int im = 0; im < 8; ++im) {
    const int row0 = m0 + wm * 128 + im * 16 + quad * 4;
#pragma unroll
    for (int j = 0; j < 3; ++j) {
      const int col = n0 + wn * 48 + j * 16 + l16;
#pragma unroll
      for (int r = 0; r < 4; ++r)
        C[(size_t)(row0 + r) * ldc + col] = (f16)acc[im][j][r];
    }
  }
}

// ------------------- 256xBN minimal-barrier NT GEMM (wo) -------------------
template <int BN>
__global__ __launch_bounds__(512, 2) void gemm_nt8(const f16* __restrict__ A,
                                                   const f16* __restrict__ B,
                                                   void* __restrict__ C,
                                                   int M, int N, int K, int ldc,
                                                   int out_f32) {
  constexpr int WN = BN / 4;
  constexpr int JN = WN / 32;
  constexpr int RB = BN / 64;
  constexpr int BUFB = BN * 128;
  extern __shared__ char smem[];
  f16* sA = (f16*)smem;
  f16* sB = (f16*)(smem + 65536);

  const int gx = gridDim.x;
  const int nwg = gx * gridDim.y;
  int bid = blockIdx.y * gx + blockIdx.x;
  if (!(nwg & 7)) bid = (bid & 7) * (nwg >> 3) + (bid >> 3);
  const int m0 = (bid / gx) * 256;
  const int n0 = (bid % gx) * BN;

  const int tid = threadIdx.x;
  const int lane = tid & 63;
  const int wave = tid >> 6;
  const int quad = lane >> 4, l16 = lane & 15;
  const int wm = wave >> 2, wn = wave & 3;

  const int srow = tid >> 3;
  const int sgr = (((tid & 7) ^ (srow & 7))) * 8;
  const f16* gA = A + (size_t)(m0 + srow) * K + sgr;
  const f16* gB = B + (size_t)(n0 + srow) * K + sgr;
  const size_t r64 = (size_t)64 * K;

  const char* cA = (const char*)sA;
  const char* cB = (const char*)sB;
  const int xm = (l16 & 7) << 4;
  const int xk0 = (quad * 16) ^ xm;
  const int xk1 = (64 + quad * 16) ^ xm;
  const int abase = (wm * 128 + l16) * 128;
  const int bbase = (wn * WN + l16) * 128;

  f32x4 acc[8][2 * JN] = {};
  const int nt = K >> 6;

#pragma unroll
  for (int a = 0; a < 4; ++a)
    async16(sA + a * 4096 + tid * 8, gA + (size_t)a * r64);
#pragma unroll
  for (int rb = 0; rb < RB; ++rb)
    async16(sB + rb * 4096 + tid * 8, gB + (size_t)rb * r64);
  asm volatile("s_waitcnt vmcnt(0)" ::: "memory");
  __builtin_amdgcn_s_barrier();

  for (int t = 0; t < nt; ++t) {
    const int bufoA = (t & 1) << 15;
    const int bufoB = (t & 1) * BUFB;
    const bool st = (t + 1 < nt);

    if (st) {
      f16* sAn = sA + (((t & 1) ^ 1) << 14);
      f16* sBn = sB + ((t & 1) ^ 1) * (BUFB / 2);
      const size_t gk = (size_t)(t + 1) * 64;
#pragma unroll
      for (int a = 0; a < 4; ++a)
        async16(sAn + a * 4096 + tid * 8, gA + a * r64 + gk);
#pragma unroll
      for (int rb = 0; rb < RB; ++rb)
        async16(sBn + rb * 4096 + tid * 8, gB + rb * r64 + gk);
    }

    f16x8 bf[2 * JN][2];
#pragma unroll
    for (int nh = 0; nh < 2; ++nh)
#pragma unroll
      for (int j = 0; j < JN; ++j) {
        bf[nh * JN + j][0] =
            DSRD(cB, bufoB + bbase + nh * (WN / 2) * 128 + j * 2048 + xk0);
        bf[nh * JN + j][1] =
            DSRD(cB, bufoB + bbase + nh * (WN / 2) * 128 + j * 2048 + xk1);
      }
#pragma unroll
    for (int mh = 0; mh < 2; ++mh) {
      f16x8 a0[4], a1[4];
#pragma unroll
      for (int i = 0; i < 4; ++i) {
        a0[i] = DSRD(cA, bufoA + abase + mh * 8192 + i * 2048 + xk0);
        a1[i] = DSRD(cA, bufoA + abase + mh * 8192 + i * 2048 + xk1);
      }
#pragma unroll
      for (int i = 0; i < 4; ++i)
#pragma unroll
        for (int j = 0; j < 2 * JN; ++j) {
          acc[mh * 4 + i][j] = __builtin_amdgcn_mfma_f32_16x16x32_f16(
              a0[i], bf[j][0], acc[mh * 4 + i][j], 0, 0, 0);
          acc[mh * 4 + i][j] = __builtin_amdgcn_mfma_f32_16x16x32_f16(
              a1[i], bf[j][1], acc[mh * 4 + i][j], 0, 0, 0);
        }
    }

    if (st) {
      asm volatile("s_waitcnt vmcnt(0)" ::: "memory");
      __builtin_amdgcn_s_barrier();
    }
  }

#pragma unroll
  for (int im = 0; im < 8; ++im) {
    const int row0 = m0 + wm * 128 + im * 16 + quad * 4;
#pragma unroll
    for (int jn = 0; jn < 2 * JN; ++jn) {
      const int col = n0 + wn * WN + jn * 16 + l16;
#pragma unroll
      for (int r = 0; r < 4; ++r) {
        const float v = acc[im][jn][r];
        if (out_f32) ((float*)C)[(size_t)(row0 + r) * ldc + col] = v;
        else         ((f16*)C)[(size_t)(row0 + r) * ldc + col] = (f16)v;
      }
    }
  }
}

// ------------------------- RMSNorm (q and k fused) -------------------------
__global__ __launch_bounds__(256) void rmsnorm2(f16* __restrict__ xqkv,
                                                const float* __restrict__ qw,
                                                const float* __restrict__ kw) {
  __shared__ float red[4];
  const int which = blockIdx.y;                   // 0 = q(2048), 1 = k(512)
  const int tid = threadIdx.x;

  auto block_sum = [&](float ss) -> float {
#pragma unroll
    for (int off = 32; off > 0; off >>= 1) ss += __shfl_down(ss, off);
    if ((tid & 63) == 0) red[tid >> 6] = ss;
    __syncthreads();
    return red[0] + red[1] + red[2] + red[3];
  };

  if (which == 0) {
    f16* p = xqkv + (size_t)blockIdx.x * LDQKV;
    f16x8 v = ((const f16x8*)p)[tid];
    float f[8];
    float ss = 0.f;
#pragma unroll
    for (int j = 0; j < 8; ++j) { f[j] = (float)v[j]; ss += f[j] * f[j]; }
    const float scale = rsqrtf(block_sum(ss) / 2048.0f + EPS_);
    const float4 w0 = ((const float4*)qw)[tid * 2];
    const float4 w1 = ((const float4*)qw)[tid * 2 + 1];
    f16x8 o;
    o[0] = (f16)(f[0] * scale * w0.x); o[1] = (f16)(f[1] * scale * w0.y);
    o[2] = (f16)(f[2] * scale * w0.z); o[3] = (f16)(f[3] * scale * w0.w);
    o[4] = (f16)(f[4] * scale * w1.x); o[5] = (f16)(f[5] * scale * w1.y);
    o[6] = (f16)(f[6] * scale * w1.z); o[7] = (f16)(f[7] * scale * w1.w);
    ((f16x8*)p)[tid] = o;
  } else {
    f16* p = xqkv + (size_t)blockIdx.x * LDQKV + 2048;
    f16x2 v = ((const f16x2*)p)[tid];
    const float f0 = (float)v[0], f1 = (float)v[1];
    const float scale = rsqrtf(block_sum(f0 * f0 + f1 * f1) / 512.0f + EPS_);
    const float2 w = ((const float2*)kw)[tid];
    f16x2 o;
    o[0] = (f16)(f0 * scale * w.x);
    o[1] = (f16)(f1 * scale * w.y);
    ((f16x2*)p)[tid] = o;
  }
}

// ------------------- K/V -> fragment-major global layout -------------------
__global__ __launch_bounds__(256) void kvfrag(const f16* __restrict__ xqkv,
                                              f16* __restrict__ Kf,
                                              f16* __restrict__ Vf) {
  __shared__ f16 Lk[64][72];
  __shared__ f16 Lv[64][72];
  const int kt = blockIdx.x;
  const int b = blockIdx.y >> 3, kh = blockIdx.y & 7;
  const int t0 = kt * 64;
  const int tid = threadIdx.x;
  const int r = tid >> 3, c = (tid & 7) * 8;
#pragma unroll
  for (int rp = 0; rp < 2; ++rp) {
    const int rr = r + rp * 32;
    const f16* src = xqkv + (size_t)(b * T_ + t0 + rr) * LDQKV + kh * 64 + c;
    *(f16x8*)(&Lk[rr][c]) = *(const f16x8*)(src + 2048);
    *(f16x8*)(&Lv[rr][c]) = *(const f16x8*)(src + 2560);
  }
  __syncthreads();
  const size_t obase = ((size_t)(b * 8 + kh) * 32 + kt) * 4096;
#pragma unroll
  for (int cc0 = 0; cc0 < 2; ++cc0) {
    const int cc = tid + cc0 * 256;
    const int nb = cc >> 7, kc = (cc >> 6) & 1, ln = cc & 63;
    const int qd = ln >> 4, s16 = ln & 15;
    *(f16x8*)(Kf + obase + cc * 8) = *(const f16x8*)(&Lk[nb * 16 + s16][kc * 32 + qd * 8]);
    f16x8 o;
#pragma unroll
    for (int j = 0; j < 8; ++j) o[j] = Lv[kc * 32 + qd * 8 + j][nb * 16 + s16];
    *(f16x8*)(Vf + obase + cc * 8) = o;
  }
}

// ---------------------------- Flash attention ------------------------------
// Round-7 kernel (72-78us measured band).  Grid: (qt2=16, h=32, b=2),
// 4 waves, barrier-free kt loop.  128 q rows per block: each wave owns TWO
// 16-row q-groups (qa/qb) sharing the same K/V fragment loads.
__global__ __launch_bounds__(256, 4) void attn(const f16* __restrict__ Q,
                                               const f16* __restrict__ Kf,
                                               const f16* __restrict__ Vf,
                                               f16* __restrict__ O) {
  constexpr int LDW = 72;
  __shared__ f16 Qs[128 * LDW];   // overlaid by per-wave P after q latch
  __shared__ float Lx[4][2][16];

  const int qt2 = 15 - blockIdx.x;   // heavy tiles dispatch first
  const int h = blockIdx.y, b = blockIdx.z;
  const int kh = h >> 2;
  const int q0 = qt2 * 128;
  const int tid = threadIdx.x;
  const int lane = tid & 63, wave = tid >> 6;
  const int quad = lane >> 4, l16 = lane & 15;
  const float scale2 = 0.125f * LOG2E;
  const float slope2 = exp2f(-0.25f * (float)h) * LOG2E;
  const float M2 = 10.0f;

  const int sr = tid >> 3, sc = (tid & 7) * 8;

  // stage Q tile (128 q x 64 d)
#pragma unroll
  for (int rp = 0; rp < 4; ++rp) {
    const int rr = sr + rp * 32;
    *(f16x8*)(Qs + rr * LDW + sc) =
        *(const f16x8*)(Q + (size_t)(b * T_ + q0 + rr) * LDQKV + h * HD + sc);
  }
  __syncthreads();   // the only block-wide barrier
  f16x8 qa[2], qb[2];
#pragma unroll
  for (int kc = 0; kc < 2; ++kc) {
    qa[kc] = *(const f16x8*)(Qs + (wave * 32 + l16) * LDW + kc * 32 + quad * 8);
    qb[kc] = *(const f16x8*)(Qs + (wave * 32 + 16 + l16) * LDW + kc * 32 + quad * 8);
  }
  f16* PsA = Qs + (wave * 32) * LDW;
  f16* PsB = Qs + (wave * 32 + 16) * LDW;

  f32x4 o0[4] = {}, o1[4] = {};
  float lsA = 0.f, lsB = 0.f;

  const int kt_lo = (q0 >= WINDOW) ? ((q0 - WINDOW) >> 6) : 0;
  const int kt_hi = (q0 + 127) >> 6;
  const int gA0 = q0 + wave * 32;
  const int gB0 = gA0 + 16;
  const int qA = gA0 + l16;
  const int qB = qA + 16;
  const f16* kfb = Kf + (size_t)(b * 8 + kh) * 131072 + lane * 8;
  const f16* vfb = Vf + (size_t)(b * 8 + kh) * 131072 + lane * 8;

  float sr4[4];
#pragma unroll
  for (int r = 0; r < 4; ++r) sr4[r] = slope2 * (float)r;
  float baseA = slope2 * (float)(kt_lo * 64 + quad * 4 - qA) - M2;
  float baseB = slope2 * (float)(kt_lo * 64 + quad * 4 - qB) - M2;
  const float bstep = slope2 * 64.0f;
  const float b16 = slope2 * 16.0f;

  for (int kt = kt_lo; kt <= kt_hi; ++kt) {
    const int k0 = kt * 64;
    const f16* kp = kfb + kt * 4096;
    const f16* vp = vfb + kt * 4096;
    const bool maskA = (k0 + 63 > gA0) || (k0 + WINDOW < gA0 + 15);
    const bool maskB = (k0 + 63 > gB0) || (k0 + WINDOW < gB0 + 15);

    float bnbA = baseA, bnbB = baseB;
#pragma unroll
    for (int nb = 0; nb < 4; ++nb) {
      const f16x8 k0f = *(const f16x8*)(kp + (nb * 2) * 512);
      const f16x8 k1f = *(const f16x8*)(kp + (nb * 2 + 1) * 512);
      f32x4 a = {0.f, 0.f, 0.f, 0.f};
      a = __builtin_amdgcn_mfma_f32_16x16x32_f16(k0f, qa[0], a, 0, 0, 0);
      a = __builtin_amdgcn_mfma_f32_16x16x32_f16(k1f, qa[1], a, 0, 0, 0);
      f32x4 c = {0.f, 0.f, 0.f, 0.f};
      c = __builtin_amdgcn_mfma_f32_16x16x32_f16(k0f, qb[0], c, 0, 0, 0);
      c = __builtin_amdgcn_mfma_f32_16x16x32_f16(k1f, qb[1], c, 0, 0, 0);

      f16x4 pkA, pkB;
#pragma unroll
      for (int r = 0; r < 4; ++r) {
        const int key = k0 + nb * 16 + quad * 4 + r;
        float vA = fmaf(a[r], scale2, bnbA + sr4[r]);
        if (maskA) {
          const int dist = key - qA;
          if (dist > 0 || dist < -WINDOW) vA = -1e30f;
        }
        const float pA = __builtin_amdgcn_exp2f(vA);
        lsA += pA;
        pkA[r] = (f16)pA;
        float vB = fmaf(c[r], scale2, bnbB + sr4[r]);
        if (maskB) {
          const int dist = key - qB;
          if (dist > 0 || dist < -WINDOW) vB = -1e30f;
        }
        const float pB = __builtin_amdgcn_exp2f(vB);
        lsB += pB;
        pkB[r] = (f16)pB;
      }
      *(f16x4*)(PsA + l16 * LDW + nb * 16 + quad * 4) = pkA;
      *(f16x4*)(PsB + l16 * LDW + nb * 16 + quad * 4) = pkB;
      bnbA += b16; bnbB += b16;
    }
    baseA += bstep; baseB += bstep;

    const f16x8 paA0 = *(const f16x8*)(PsA + l16 * LDW + quad * 8);
    const f16x8 paA1 = *(const f16x8*)(PsA + l16 * LDW + 32 + quad * 8);
    const f16x8 paB0 = *(const f16x8*)(PsB + l16 * LDW + quad * 8);
    const f16x8 paB1 = *(const f16x8*)(PsB + l16 * LDW + 32 + quad * 8);
#pragma unroll
    for (int nb = 0; nb < 4; ++nb) {
      const f16x8 v0 = *(const f16x8*)(vp + (nb * 2) * 512);
      const f16x8 v1 = *(const f16x8*)(vp + (nb * 2 + 1) * 512);
      o0[nb] = __builtin_amdgcn_mfma_f32_16x16x32_f16(paA0, v0, o0[nb], 0, 0, 0);
      o0[nb] = __builtin_amdgcn_mfma_f32_16x16x32_f16(paA1, v1, o0[nb], 0, 0, 0);
      o1[nb] = __builtin_amdgcn_mfma_f32_16x16x32_f16(paB0, v0, o1[nb], 0, 0, 0);
      o1[nb] = __builtin_amdgcn_mfma_f32_16x16x32_f16(paB1, v1, o1[nb], 0, 0, 0);
    }
  }

  lsA += __shfl_xor(lsA, 16);
  lsA += __shfl_xor(lsA, 32);
  lsB += __shfl_xor(lsB, 16);
  lsB += __shfl_xor(lsB, 32);
  if (quad == 0) { Lx[wave][0][l16] = lsA; Lx[wave][1][l16] = lsB; }
  float rlA[4], rlB[4];
#pragma unroll
  for (int r = 0; r < 4; ++r) {
    rlA[r] = 1.0f / Lx[wave][0][quad * 4 + r];
    rlB[r] = 1.0f / Lx[wave][1][quad * 4 + r];
  }

#pragma unroll
  for (int r = 0; r < 4; ++r) {
    const int qrA = q0 + wave * 32 + quad * 4 + r;
#pragma unroll
    for (int nb = 0; nb < 4; ++nb) {
      O[(size_t)(b * T_ + qrA) * (NH * HD) + h * HD + nb * 16 + l16] =
          (f16)(o0[nb][r] * rlA[r]);
      O[(size_t)(b * T_ + qrA + 16) * (NH * HD) + h * HD + nb * 16 + l16] =
          (f16)(o1[nb][r] * rlB[r]);
    }
  }
}

// ------------------------------- launcher ----------------------------------
extern "C" void kernel_launch(void* const* d_in, const int* in_sizes, int n_in,
                              void* d_out, int out_size, void* d_ws, size_t ws_size,
                              hipStream_t stream) {
  const float* x  = (const float*)d_in[0];
  const float* wq = (const float*)d_in[1];
  const float* wk = (const float*)d_in[2];
  const float* wv = (const float*)d_in[3];
  const float* wo = (const float*)d_in[4];
  const float* qw = (const float*)d_in[5];
  const float* kw = (const float*)d_in[6];
  float* out = (float*)d_out;

  char* ws = (char*)d_ws;
  size_t off = 0;
  auto carve = [&](size_t bytes) -> char* {
    char* p = ws + off;
    off += (bytes + 255) & ~(size_t)255;
    return p;
  };
  f16* xh    = (f16*)carve((size_t)4096 * 2048 * 2);  // x f16; later attn out
  f16* wqkvh = (f16*)carve((size_t)3072 * 2048 * 2);
  f16* woh   = (f16*)carve((size_t)2048 * 2048 * 2);
  f16* xqkv  = (f16*)carve((size_t)4096 * 3072 * 2);
  // After the QKV GEMM the wq rows of wqkvh are dead: reuse for K/V frags.
  f16* Kf = wqkvh;                          // 16 x 128K f16 = 4MB
  f16* Vf = wqkvh + (size_t)16 * 131072;    // 4MB
  f16* ao = xh;

  static bool attr_done = false;
  if (!attr_done) {
    (void)hipFuncSetAttribute((const void*)gemm_nt192,
                              hipFuncAttributeMaxDynamicSharedMemorySize,
                              114688);
    (void)hipFuncSetAttribute((const void*)gemm_nt8<128>,
                              hipFuncAttributeMaxDynamicSharedMemorySize,
                              98304);
    attr_done = true;
  }

  CvtArgs ca;
  ca.src[0] = x;  ca.dst[0] = xh;                            ca.n4[0] = (4096 * 2048) / 4;
  ca.src[1] = wq; ca.dst[1] = wqkvh;                         ca.n4[1] = (2048 * 2048) / 4;
  ca.src[2] = wk; ca.dst[2] = wqkvh + (size_t)2048 * 2048;   ca.n4[2] = (512 * 2048) / 4;
  ca.src[3] = wv; ca.dst[3] = wqkvh + (size_t)2560 * 2048;   ca.n4[3] = (512 * 2048) / 4;
  ca.src[4] = wo; ca.dst[4] = woh;                           ca.n4[4] = (2048 * 2048) / 4;
  cvt_multi<<<dim3(1024, 5), 256, 0, stream>>>(ca);

  gemm_nt192<<<dim3(16, 16), 512, 114688, stream>>>(xh, wqkvh, xqkv);
  rmsnorm2<<<dim3(4096, 2), 256, 0, stream>>>(xqkv, qw, kw);
  kvfrag<<<dim3(32, 16), 256, 0, stream>>>(xqkv, Kf, Vf);
  attn<<<dim3(16, 32, 2), 256, 0, stream>>>(xqkv, Kf, Vf, ao);
  gemm_nt8<128><<<dim3(16, 16), 512, 98304, stream>>>(ao, woh, out, 4096, 2048, 2048, 2048, 1);
}